// Round 5
// baseline (473.689 us; speedup 1.0000x reference)
//
#include <hip/hip_runtime.h>
#include <hip/hip_bf16.h>

typedef __attribute__((ext_vector_type(4))) float  f32x4;
typedef __attribute__((ext_vector_type(8))) __bf16 bf16x8;
typedef __attribute__((ext_vector_type(4))) __bf16 bf16x4;

#define NB 2
#define NN 100000
#define NE 400000

__device__ __forceinline__ float tanh_f(float x) {
  float xc = fminf(fmaxf(x, -10.f), 10.f);
  float e = __expf(2.f * xc);
  return 1.f - 2.f / (e + 1.f);
}

// dtype-branched float load: bf=1 -> buffer is bf16, bf=0 -> fp32
__device__ __forceinline__ float ldf(const void* p, long i, int bf) {
  return bf ? (float)((const __bf16*)p)[i] : ((const float*)p)[i];
}

// permuted dim assignment: GEMM1 tile nt, row -> h-dim. Chosen so that the
// GEMM1 C-layout accumulators (after tanh+pack) ARE the GEMM2 B-fragments
// in-lane with standard k ordering. HW-verified via round-4 Output 0 pass.
__device__ __host__ __forceinline__ int fdim(int nt, int row) {
  return 32 * (nt >> 1) + 4 * (nt & 1) + 8 * (row >> 2) + 2 * ((row >> 1) & 1) + (row & 1);
}

// ---------- one-block setup: dtype detect + h_num MLP + weight-fragment pack ----------
// flags[0]=mask-is-bytes, flags[1]=inputs-are-bf16
__global__ __launch_bounds__(256) void k_setup(
    const unsigned int* __restrict__ mw, const unsigned int* __restrict__ nodew,
    const void* __restrict__ numerical, const void* __restrict__ W1,
    const void* __restrict__ b1, const void* __restrict__ W2,
    const void* __restrict__ b2, const void* __restrict__ Wn,
    const void* __restrict__ bn, const void* __restrict__ We,
    int* __restrict__ flags, float* __restrict__ hnum,
    float* __restrict__ sums, float* __restrict__ counts,
    __bf16* __restrict__ packWnT, __bf16* __restrict__ packWe,
    float* __restrict__ packBn) {
  __shared__ int badS, goodS, dtS;
  __shared__ float numf[2][32];
  __shared__ float u[2][128];
  const int t = threadIdx.x;
  if (t == 0) { badS = 0; goodS = 0; }
  __syncthreads();
  int my = 0;
  for (int i = t; i < 4096; i += 256) my |= (mw[i] > 1u) ? 1 : 0;
  if (my) atomicOr(&badS, 1);
  int g = 0;
  for (int i = t; i < 4096; i += 256) {
    unsigned lo = nodew[i] & 0xFFFFu;
    unsigned e = (lo >> 7) & 0xFFu;
    g += (lo == 0u || (e >= 100u && e <= 141u)) ? 1 : 0;
  }
  atomicAdd(&goodS, g);
  __syncthreads();
  if (t == 0) {
    flags[0] = badS;
    dtS = (goodS > 2048) ? 1 : 0;
    flags[1] = dtS;
  }
  __syncthreads();
  const int dt = dtS;

  if (t < 128) sums[t] = 0.f;
  if (t < 2) counts[t] = 0.f;
  if (t < 64) numf[t >> 5][t & 31] = ldf(numerical, t, dt);
  __syncthreads();
  {
    const int b = t >> 7, j = t & 127;
    float acc = ldf(b1, j, dt);
#pragma unroll
    for (int k = 0; k < 32; ++k) acc += numf[b][k] * ldf(W1, k * 128 + j, dt);
    u[b][j] = tanh_f(acc);
  }
  __syncthreads();
  if (t < 128) {
    const int b = t >> 6, d = t & 63;
    float acc = ldf(b2, d, dt);
#pragma unroll
    for (int k = 0; k < 128; ++k) acc += u[b][k] * ldf(W2, k * 64 + d, dt);
    hnum[b * 64 + d] = tanh_f(acc);
  }

  if (t < 64) {
    const int m = t & 15, quad = t >> 4;
    // GEMM1 A-operand: Wn^T with permuted dim->(tile,row) assignment
#pragma unroll
    for (int nt = 0; nt < 4; ++nt) {
      const int dim = fdim(nt, m);
#pragma unroll
      for (int j = 0; j < 8; ++j)
        packWnT[t * 32 + nt * 8 + j] = (__bf16)ldf(Wn, (quad * 8 + j) * 64 + dim, dt);
#pragma unroll
      for (int r = 0; r < 4; ++r)
        packBn[t * 16 + nt * 4 + r] = ldf(bn, fdim(nt, quad * 4 + r), dt);
    }
    // GEMM2 A-operand: concat-We^T, standard order. concatWe[k][c2] =
    //   c2<64 ? We[k][c2] : We[k+64][c2-64]
#pragma unroll
    for (int f = 0; f < 16; ++f) {
      const int nt = f >> 1, kh = f & 1;
      const int c2 = m + 16 * nt;
#pragma unroll
      for (int j = 0; j < 8; ++j) {
        const int k = kh * 32 + quad * 8 + j;
        packWe[t * 128 + f * 8 + j] =
            (__bf16)((c2 < 64) ? ldf(We, k * 64 + c2, dt)
                               : ldf(We, (k + 64) * 64 + (c2 - 64), dt));
      }
    }
  }
}

// ---------- per-node MFMA (transposed, LDS-free, barrier-free) ----------
// D1 = Wn^T(permuted) @ node^T (+bn), tanh; D2 = concatWe^T @ h^T -> AB.
// Wave handles 16 nodes; block 256 = 64 nodes; grid 3125.
__global__ __launch_bounds__(256) void k_nodes(
    const void* __restrict__ node, const __bf16* __restrict__ packWnT,
    const __bf16* __restrict__ packWe, const float* __restrict__ packBn,
    const int* __restrict__ flags, __bf16* __restrict__ AB) {
  const int t = threadIdx.x;
  const int wave = t >> 6, lane = t & 63;
  const int m = lane & 15, quad = lane >> 4;
  const int dt = flags[1];

  bf16x8 wnF[4];
#pragma unroll
  for (int nt = 0; nt < 4; ++nt)
    wnF[nt] = *(const bf16x8*)(packWnT + lane * 32 + nt * 8);
  bf16x8 weF[16];
#pragma unroll
  for (int f2 = 0; f2 < 16; ++f2)
    weF[f2] = *(const bf16x8*)(packWe + lane * 128 + f2 * 8);
  f32x4 bnv[4];
#pragma unroll
  for (int nt = 0; nt < 4; ++nt)
    bnv[nt] = *(const f32x4*)(packBn + lane * 16 + nt * 4);

  const long r0 = ((long)blockIdx.x * 4 + wave) * 16;
  // B-operand: node features of node (r0+m), k = quad*8+j (16 contiguous B)
  bf16x8 aF;
  if (dt) {
    aF = *(const bf16x8*)((const __bf16*)node + (r0 + m) * 32 + quad * 8);
  } else {
    const float* p = (const float*)node + (r0 + m) * 32 + quad * 8;
    f32x4 v0 = *(const f32x4*)p, v1 = *(const f32x4*)(p + 4);
#pragma unroll
    for (int j = 0; j < 4; ++j) { aF[j] = (__bf16)v0[j]; aF[4 + j] = (__bf16)v1[j]; }
  }

  f32x4 acc[4];
#pragma unroll
  for (int nt = 0; nt < 4; ++nt) acc[nt] = bnv[nt];
#pragma unroll
  for (int nt = 0; nt < 4; ++nt)
    acc[nt] = __builtin_amdgcn_mfma_f32_16x16x32_bf16(wnF[nt], aF, acc[nt], 0, 0, 0);

  // tanh + pack: thanks to the fdim permutation, these are exactly the
  // GEMM2 B-fragments (h[node][32kh+8q+j]) in-lane.
  bf16x8 hF[2];
#pragma unroll
  for (int kh = 0; kh < 2; ++kh)
#pragma unroll
    for (int j = 0; j < 8; ++j)
      hF[kh][j] = (__bf16)tanh_f(acc[2 * kh + (j >> 2)][j & 3]);

  f32x4 accB[8];
#pragma unroll
  for (int f = 0; f < 8; ++f) {
    f32x4 z; z[0] = 0.f; z[1] = 0.f; z[2] = 0.f; z[3] = 0.f;
    accB[f] = z;
  }
#pragma unroll
  for (int f = 0; f < 8; ++f) {
    accB[f] = __builtin_amdgcn_mfma_f32_16x16x32_bf16(weF[2 * f], hF[0], accB[f], 0, 0, 0);
    accB[f] = __builtin_amdgcn_mfma_f32_16x16x32_bf16(weF[2 * f + 1], hF[1], accB[f], 0, 0, 0);
  }

  // D2[dim2=16f+4q+r][node=m]: 4 consecutive dims per reg quad -> 8-B stores
  __bf16* rowp = AB + (r0 + m) * 128 + quad * 4;
#pragma unroll
  for (int f = 0; f < 8; ++f) {
    bf16x4 o;
#pragma unroll
    for (int r = 0; r < 4; ++r) o[r] = (__bf16)accB[f][r];
    *(bf16x4*)(rowp + f * 16) = o;
  }
}

// ---------- per-edge: 128 edges/block, 2 barrier-free passes, one staged store ----------
// NE = 400000 = 128 * 3125 exactly -> no bounds guards.
__global__ __launch_bounds__(256) void k_edges(
    const int2* __restrict__ eidx, const void* __restrict__ emask,
    const int* __restrict__ flags, const __bf16* __restrict__ AB,
    const void* __restrict__ be, float* __restrict__ sums,
    float* __restrict__ counts, float* __restrict__ outp) {
  const int nbPerB = NE / 128;  // 3125
  const int b = blockIdx.x / nbPerB;
  const long e0 = (long)(blockIdx.x % nbPerB) * 128;
  const int t = threadIdx.x;
  const int L = t & 3, eo = t >> 2;
  const int wave = t >> 6, lane = t & 63;
  __shared__ float beL[64];
  __shared__ float stageF[128 * 68];  // 128 edges x 64 floats, stride 68 (2-way banks = free)
  __shared__ float waveRed[4][64];
  __shared__ float waveCnt[4];
  const int dt = flags[1];
  const int mode = flags[0];
  if (t < 64) beL[t] = ldf(be, t, dt);
  __syncthreads();
  const __bf16* ABb = AB + (long)b * NN * 128;
  const int d0 = L * 16;
  float psum[16];
#pragma unroll
  for (int k = 0; k < 16; ++k) psum[k] = 0.f;
  float pcnt = 0.f;

#pragma unroll
  for (int pass = 0; pass < 2; ++pass) {
    const int e128 = pass * 64 + eo;
    const long e = e0 + e128;
    const int2 ij = eidx[(long)b * NE + e];
    float mval;
    if (mode) mval = (float)(((const unsigned char*)emask)[(long)b * NE + e]);
    else      mval = (float)(((const int*)emask)[(long)b * NE + e]);
    const __bf16* Ri = ABb + (long)ij.x * 128;
    const __bf16* Rj = ABb + (long)ij.y * 128;
    bf16x8 ai0 = *(const bf16x8*)(Ri + d0);
    bf16x8 ai1 = *(const bf16x8*)(Ri + d0 + 8);
    bf16x8 bi0 = *(const bf16x8*)(Ri + 64 + d0);
    bf16x8 bi1 = *(const bf16x8*)(Ri + 64 + d0 + 8);
    bf16x8 aj0 = *(const bf16x8*)(Rj + d0);
    bf16x8 aj1 = *(const bf16x8*)(Rj + d0 + 8);
    bf16x8 bj0 = *(const bf16x8*)(Rj + 64 + d0);
    bf16x8 bj1 = *(const bf16x8*)(Rj + 64 + d0 + 8);
    float ov[16];
#pragma unroll
    for (int k = 0; k < 8; ++k) {
      const float bias = beL[d0 + k];
      const float s12 = (float)ai0[k] + (float)bj0[k] + bias;
      const float s21 = (float)aj0[k] + (float)bi0[k] + bias;
      const float v = 0.5f * (tanh_f(s12) + tanh_f(s21)) * mval;
      psum[k] += v;
      ov[k] = v;
    }
#pragma unroll
    for (int k = 0; k < 8; ++k) {
      const float bias = beL[d0 + 8 + k];
      const float s12 = (float)ai1[k] + (float)bj1[k] + bias;
      const float s21 = (float)aj1[k] + (float)bi1[k] + bias;
      const float v = 0.5f * (tanh_f(s12) + tanh_f(s21)) * mval;
      psum[8 + k] += v;
      ov[8 + k] = v;
    }
    if (L == 0) pcnt += mval;  // masked-edge count (restored: round-4 bug)
    // stage into LDS (edge-major, stride 68 floats)
#pragma unroll
    for (int u = 0; u < 4; ++u) {
      f32x4 w; w[0] = ov[4 * u]; w[1] = ov[4 * u + 1];
      w[2] = ov[4 * u + 2]; w[3] = ov[4 * u + 3];
      *(f32x4*)&stageF[e128 * 68 + L * 16 + 4 * u] = w;
    }
  }
  __syncthreads();  // the ONLY barrier between gathers and store burst

  // coalesced NT store burst: consecutive lanes write consecutive 16-B chunks
  {
    float* pb = outp + ((long)b * NE + e0) * 64;
#pragma unroll
    for (int i = 0; i < 8; ++i) {
      const int c = i * 256 + t;  // c in [0,2048): (edge128 = c>>4, chunk = c&15)
      f32x4 v = *(const f32x4*)&stageF[(c >> 4) * 68 + (c & 15) * 4];
      __builtin_nontemporal_store(v, (f32x4*)(pb + c * 4));
    }
  }

  // wave-level butterfly over eo bits (lane bits 2..5), then tiny LDS combine
#pragma unroll
  for (int s = 4; s <= 32; s <<= 1) {
#pragma unroll
    for (int k = 0; k < 16; ++k) psum[k] += __shfl_xor(psum[k], s);
    pcnt += __shfl_xor(pcnt, s);
  }
  if (lane < 4) {
#pragma unroll
    for (int k = 0; k < 16; ++k) waveRed[wave][lane * 16 + k] = psum[k];
  }
  if (lane == 0) waveCnt[wave] = pcnt;
  __syncthreads();
  if (t < 64) {
    float s = waveRed[0][t] + waveRed[1][t] + waveRed[2][t] + waveRed[3][t];
    atomicAdd(&sums[b * 64 + t], s);
  }
  if (t == 0) {
    atomicAdd(&counts[b], waveCnt[0] + waveCnt[1] + waveCnt[2] + waveCnt[3]);
  }
}

// ---------- finalize state_value = [h_num | mean | stage] (fp32 out) ----------
__global__ __launch_bounds__(512) void k_final(
    const float* __restrict__ hnum, const float* __restrict__ sums,
    const float* __restrict__ counts, const void* __restrict__ stage,
    const int* __restrict__ flags, float* __restrict__ out) {
  const int t = threadIdx.x;
  const int dt = flags[1];
  if (t < 260) {
    const int b = t / 130, c = t % 130;
    float v;
    if (c < 64) v = hnum[b * 64 + c];
    else if (c < 128) v = sums[b * 64 + (c - 64)] / counts[b];
    else v = ldf(stage, b * 2 + (c - 128), dt);
    out[(long)NB * NE * 64 + (long)b * 130 + c] = v;
  }
}

extern "C" void kernel_launch(void* const* d_in, const int* in_sizes, int n_in,
                              void* d_out, int out_size, void* d_ws, size_t ws_size,
                              hipStream_t stream) {
  const void* numerical = d_in[0];
  const void* node      = d_in[1];
  const int2* eidx      = (const int2*)d_in[2];
  const void* emask     = d_in[3];
  const void* stage     = d_in[4];
  const void* W1 = d_in[5];
  const void* b1 = d_in[6];
  const void* W2 = d_in[7];
  const void* b2 = d_in[8];
  const void* Wn = d_in[9];
  const void* bn = d_in[10];
  const void* We = d_in[11];
  const void* be = d_in[12];

  char* ws = (char*)d_ws;
  int*    flags   = (int*)ws;
  float*  sums    = (float*)(ws + 256);     // [2][64]
  float*  counts  = (float*)(ws + 1024);    // [2]
  float*  hnum    = (float*)(ws + 1280);    // [2][64]
  float*  packBn  = (float*)(ws + 2048);    // 64*16*4B = 4 KB
  __bf16* packWnT = (__bf16*)(ws + 6144);   // 64*32*2B = 4 KB
  __bf16* packWe  = (__bf16*)(ws + 10240);  // 64*128*2B = 16 KB
  __bf16* AB      = (__bf16*)(ws + 32768);  // 200000*128*2B = 51.2 MB
  float*  outp    = (float*)d_out;

  k_setup<<<1, 256, 0, stream>>>((const unsigned int*)emask, (const unsigned int*)node,
                                 numerical, W1, b1, W2, b2, Wn, bn, We,
                                 flags, hnum, sums, counts, packWnT, packWe, packBn);
  k_nodes<<<(NB * NN) / 64, 256, 0, stream>>>(node, packWnT, packWe, packBn, flags, AB);
  k_edges<<<NB * (NE / 128), 256, 0, stream>>>(eidx, emask, flags, AB, be, sums, counts, outp);
  k_final<<<1, 512, 0, stream>>>(hnum, sums, counts, stage, flags, outp);
}